// Round 9
// baseline (124.266 us; speedup 1.0000x reference)
//
#include <hip/hip_runtime.h>

#define NEG_SLOPE 0.2f

typedef float f32x4 __attribute__((ext_vector_type(4)));
typedef short bf16x8 __attribute__((ext_vector_type(8)));

// ---- bf16 helpers (raw-bit, RNE) ----
__device__ __forceinline__ unsigned short f2bf(float f) {
  union { float f; unsigned u; } v; v.f = f;
  unsigned r = v.u + 0x7fff + ((v.u >> 16) & 1);
  return (unsigned short)(r >> 16);
}
__device__ __forceinline__ float bf2f(unsigned short u) {
  union { unsigned u; float f; } v; v.u = ((unsigned)u) << 16;
  return v.f;
}
__device__ __forceinline__ unsigned pkbf(float a, float b) {
  return (unsigned)f2bf(a) | ((unsigned)f2bf(b) << 16);
}
__device__ __forceinline__ f32x4 upk4(unsigned ux, unsigned uy) {
  union { unsigned u; float f; } a, b, c, d;
  a.u = ux << 16; b.u = ux & 0xffff0000u;
  c.u = uy << 16; d.u = uy & 0xffff0000u;
  f32x4 r; r.x = a.f; r.y = b.f; r.z = c.f; r.w = d.f;
  return r;
}
// fused |s|*coef + d (abs folds as input modifier)
__device__ __forceinline__ f32x4 absfma(f32x4 s, f32x4 coef, f32x4 d) {
  d.x = fmaf(fabsf(s.x), coef.x, d.x);
  d.y = fmaf(fabsf(s.y), coef.y, d.y);
  d.z = fmaf(fabsf(s.z), coef.z, d.z);
  d.w = fmaf(fabsf(s.w), coef.w, d.w);
  return d;
}
// x + (x from lane^1) via DPP quad_perm [1,0,3,2] — pure VALU, no DS pipe
__device__ __forceinline__ float dpp_xor1_add(float x) {
  int y = __builtin_amdgcn_mov_dpp(__builtin_bit_cast(int, x), 0xB1, 0xF, 0xF, true);
  return x + __builtin_bit_cast(float, y);
}

// -------- MFMA GEMM: hb[N,64](bf16) = x[N,128] @ W[128,64] --------
// mfma_f32_16x16x32_bf16. x split hi+lo bf16 (2 MFMAs) so dot error ~ W only.
__global__ __launch_bounds__(256) void gemm_mfma(const float* __restrict__ x,
                                                 const float* __restrict__ W,
                                                 unsigned short* __restrict__ hb, int N) {
  __shared__ uint4 Bl[1024];  // [ct*4+kt][lane] : 16B B-fragments
  const int t = threadIdx.x;
  {
    const int l = t & 63;
    const int kt = (t >> 6) & 3;
    const int kb = kt * 32 + ((l >> 4) * 8);
    const int cb = l & 15;
#pragma unroll
    for (int ct = 0; ct < 4; ct++) {
      const float* wp = W + (size_t)kb * 64 + ct * 16 + cb;
      unsigned p[4];
#pragma unroll
      for (int jj = 0; jj < 4; jj++)
        p[jj] = pkbf(wp[(2 * jj) * 64], wp[(2 * jj + 1) * 64]);
      Bl[(ct * 4 + kt) * 64 + l] = make_uint4(p[0], p[1], p[2], p[3]);
    }
  }
  __syncthreads();
  const int l = t & 63;
  const int wv = t >> 6;
  union BU { bf16x8 v; uint4 q; };
  BU b[4][4];
#pragma unroll
  for (int ct = 0; ct < 4; ct++)
#pragma unroll
    for (int kt = 0; kt < 4; kt++) b[ct][kt].q = Bl[(ct * 4 + kt) * 64 + l];

  const int rowbase0 = blockIdx.x * 256 + wv * 64;
#pragma unroll
  for (int rt = 0; rt < 4; rt++) {
    const int rbase = rowbase0 + rt * 16;
    int rl = rbase + (l & 15);
    if (rl >= N) rl = N - 1;
    const float* xp = x + (size_t)rl * 128 + ((l >> 4) * 8);
    BU ah[4], alo[4];
#pragma unroll
    for (int kt = 0; kt < 4; kt++) {
      float f[8];
      float4 v0 = *(const float4*)(xp + kt * 32);
      float4 v1 = *(const float4*)(xp + kt * 32 + 4);
      f[0] = v0.x; f[1] = v0.y; f[2] = v0.z; f[3] = v0.w;
      f[4] = v1.x; f[5] = v1.y; f[6] = v1.z; f[7] = v1.w;
      unsigned short hs[8], ls[8];
#pragma unroll
      for (int j = 0; j < 8; j++) {
        hs[j] = f2bf(f[j]);
        ls[j] = f2bf(f[j] - bf2f(hs[j]));
      }
      ah[kt].q = make_uint4(hs[0] | (hs[1] << 16), hs[2] | (hs[3] << 16),
                            hs[4] | (hs[5] << 16), hs[6] | (hs[7] << 16));
      alo[kt].q = make_uint4(ls[0] | (ls[1] << 16), ls[2] | (ls[3] << 16),
                             ls[4] | (ls[5] << 16), ls[6] | (ls[7] << 16));
    }
#pragma unroll
    for (int ct = 0; ct < 4; ct++) {
      f32x4 acc = {0.f, 0.f, 0.f, 0.f};
#pragma unroll
      for (int kt = 0; kt < 4; kt++) {
        acc = __builtin_amdgcn_mfma_f32_16x16x32_bf16(ah[kt].v, b[ct][kt].v, acc, 0, 0, 0);
        acc = __builtin_amdgcn_mfma_f32_16x16x32_bf16(alo[kt].v, b[ct][kt].v, acc, 0, 0, 0);
      }
#pragma unroll
      for (int j = 0; j < 4; j++) {
        float v = acc[j];
        float pv = __shfl_xor(v, 1);
        int row = rbase + (l >> 4) * 4 + j;
        if (!(l & 1) && row < N) {
          *(unsigned*)((char*)hb + (size_t)row * 128 + ct * 32 + (l & 15) * 2) =
              pkbf(v, pv);
        }
      }
    }
  }
}

// -------- Pass 1: bucket edges by row>>9, LDS-compacted writes --------
#define TILE 4096
#define EPT 16
#define NBKT_MAX 256

__global__ __launch_bounds__(256) void bucket_pass(const int* __restrict__ rowi,
                                                   const int* __restrict__ coli,
                                                   int* __restrict__ bucket_fill,
                                                   unsigned* __restrict__ bucket_arr,
                                                   int E, int Cedge, int Ctot, int NBKT) {
  __shared__ int cnt[NBKT_MAX];
  __shared__ int excl[NBKT_MAX];
  __shared__ int gadj[NBKT_MAX];
  __shared__ int tmp[NBKT_MAX];
  __shared__ unsigned staged[TILE];
  __shared__ unsigned char bkof[TILE];
  const int t = threadIdx.x;
  const int tile0 = blockIdx.x * TILE;
  const int nt = min(TILE, E - tile0);
  cnt[t] = 0;
  __syncthreads();
  unsigned pk[EPT];
  int bk[EPT];
#pragma unroll
  for (int j = 0; j < EPT; j++) {
    int i = tile0 + j * 256 + t;
    if (i < E) {
      int r = rowi[i];
      int c = coli[i];
      bk[j] = r >> 9;
      pk[j] = ((unsigned)(r & 511) << 17) | (unsigned)c;
      atomicAdd(&cnt[bk[j]], 1);
    } else {
      bk[j] = -1;
    }
  }
  __syncthreads();
  // 256-wide inclusive scan of cnt
  int v = cnt[t];
  tmp[t] = v;
  __syncthreads();
  for (int off = 1; off < 256; off <<= 1) {
    int val = tmp[t] + ((t >= off) ? tmp[t - off] : 0);
    __syncthreads();
    tmp[t] = val;
    __syncthreads();
  }
  int ex = tmp[t] - v;
  excl[t] = ex;
  int ga = 0;
  if (v > 0) ga = atomicAdd(&bucket_fill[t], v);
  gadj[t] = ga - ex;  // global_pos_in_bucket = local_stage_idx + gadj[b]
  cnt[t] = ex;        // cursor
  __syncthreads();
  // scatter into LDS stage (grouped by bucket)
#pragma unroll
  for (int j = 0; j < EPT; j++) {
    if (bk[j] >= 0) {
      int lp = atomicAdd(&cnt[bk[j]], 1);
      staged[lp] = pk[j];
      bkof[lp] = (unsigned char)bk[j];
    }
  }
  __syncthreads();
  // monotonic copy-out
  for (int i = t; i < nt; i += 256) {
    int b = bkof[i];
    int pb = i + gadj[b];
    if (pb < Cedge) bucket_arr[b * Ctot + pb] = staged[i];
  }
}

// -------- Pass 2: per-bucket counting sort -> CSR (in-place) --------
// hist init = 1 per valid row (self-loop slot); self entry appended after
// the edge scatter. rowinfo[r] = {offs, end} packed int2.
#define STAGE_CAP 10240

__global__ __launch_bounds__(256) void csr_pass(unsigned* __restrict__ bucket_arr,
                                                const int* __restrict__ bucket_fill,
                                                int2* __restrict__ rowinfo,
                                                int Cedge, int Ctot, int N) {
  __shared__ unsigned stage[STAGE_CAP];
  __shared__ int hist[512], excl[512], pairs[256];
  const int t = threadIdx.x;
  const int b = blockIdx.x;
  const int bb = b * Ctot;
  const int r0 = b << 9;
  const int nb = min(bucket_fill[b], Cedge);
  for (int i = t; i < 512; i += 256) hist[i] = ((r0 + i) < N) ? 1 : 0;  // self slot
  for (int i = t; i < nb; i += 256) stage[i] = bucket_arr[bb + i];
  __syncthreads();
  for (int i = t; i < nb; i += 256) atomicAdd(&hist[stage[i] >> 17], 1);
  __syncthreads();
  int h0 = hist[2 * t], h1 = hist[2 * t + 1];
  int ps = h0 + h1;
  pairs[t] = ps;
  __syncthreads();
  for (int off = 1; off < 256; off <<= 1) {
    int val = pairs[t] + ((t >= off) ? pairs[t - off] : 0);
    __syncthreads();
    pairs[t] = val;
    __syncthreads();
  }
  int pexcl = pairs[t] - ps;
  excl[2 * t] = pexcl;
  excl[2 * t + 1] = pexcl + h0;
  __syncthreads();
  for (int r = t; r < 512; r += 256) {
    int gr = r0 + r;
    if (gr < N) {
      int o = bb + excl[r];
      rowinfo[gr] = make_int2(o, o + hist[r]);
    }
  }
  __syncthreads();
  for (int i = t; i < nb; i += 256) {
    unsigned pk = stage[i];
    int r = pk >> 17;
    int lp = atomicAdd(&excl[r], 1);
    bucket_arr[bb + lp] = (pk & 0x1FFFFu) << 7;  // pre-scaled byte offset
  }
  __syncthreads();
  // append self entries (cursor now = offs + nedges = last slot)
  for (int r = t; r < 512; r += 256) {
    int gr = r0 + r;
    if (gr < N) bucket_arr[bb + excl[r]] = (unsigned)gr << 7;
  }
}

// -------- Node pass: one wave/node, 8 ch/lane, 8 edge streams --------
// lane = s*8+lr: lr owns channels 8lr..8lr+7 (head = lr>>1), stream s owns
// edge k+s. Head reduce = 1 DPP xor1 add (16 ch = 2 lanes). leaky*att folded:
// attA*s + attB*|s| (attA=0.6att, attB=0.4att).
#define ESTEP8(u, gate)                                  \
  {                                                      \
    f32x4 ja = upk4((u).x, (u).y);                       \
    f32x4 jb = upk4((u).z, (u).w);                       \
    f32x4 sa = hia + ja, sb = hib + jb;                  \
    f32x4 da = sa * attAa, db = sb * attAb;              \
    da = absfma(sa, attBa, da);                          \
    db = absfma(sb, attBb, db);                          \
    float al = ((da.x + da.y) + (da.z + da.w)) +         \
               ((db.x + db.y) + (db.z + db.w));          \
    al = dpp_xor1_add(al);                               \
    float p = (gate) ? __expf(al) : 0.f;                 \
    acca += ja * p;                                      \
    accb += jb * p;                                      \
    den += p;                                            \
  }

__global__ __launch_bounds__(256) void node_pass(const unsigned short* __restrict__ hb,
                                                 const int2* __restrict__ rowinfo,
                                                 const unsigned* __restrict__ srcs,
                                                 const float* __restrict__ att,
                                                 const float* __restrict__ bias,
                                                 float* __restrict__ out, int N) {
  int w = (blockIdx.x * blockDim.x + threadIdx.x) >> 6;
  if (w >= N) return;
  const int lane = threadIdx.x & 63;
  const int lr = lane & 7;
  const int s = lane >> 3;
  const char* hbc = (const char*)hb;
  const unsigned loff = (unsigned)(lr << 4);
  const f32x4 attAa = *(const f32x4*)(att + 8 * lr) * 0.6f;
  const f32x4 attAb = *(const f32x4*)(att + 8 * lr + 4) * 0.6f;
  const f32x4 attBa = *(const f32x4*)(att + 8 * lr) * 0.4f;
  const f32x4 attBb = *(const f32x4*)(att + 8 * lr + 4) * 0.4f;
  const int2 oi = rowinfo[w];
  int k = oi.x;
  const int k1 = oi.y;
  uint4 hv = *(const uint4*)(hbc + (((unsigned)w << 7) | loff));
  const f32x4 hia = upk4(hv.x, hv.y);
  const f32x4 hib = upk4(hv.z, hv.w);
  f32x4 acca = {0.f, 0.f, 0.f, 0.f};
  f32x4 accb = {0.f, 0.f, 0.f, 0.f};
  float den = 0.f;
  for (; k + 16 <= k1; k += 16) {
    unsigned o0 = srcs[k + s] | loff;
    unsigned o1 = srcs[k + 8 + s] | loff;
    uint4 u0 = *(const uint4*)(hbc + o0);
    uint4 u1 = *(const uint4*)(hbc + o1);
    ESTEP8(u0, true);
    ESTEP8(u1, true);
  }
  for (; k + 8 <= k1; k += 8) {
    unsigned o = srcs[k + s] | loff;
    uint4 u = *(const uint4*)(hbc + o);
    ESTEP8(u, true);
  }
  if (k < k1) {
    bool act = (k + s) < k1;
    unsigned o = (act ? srcs[k + s] : srcs[k]) | loff;
    uint4 u = *(const uint4*)(hbc + o);
    ESTEP8(u, act);
  }
  // combine 8 streams
#pragma unroll
  for (int j = 0; j < 4; j++) {
    acca[j] += __shfl_xor(acca[j], 8);
    accb[j] += __shfl_xor(accb[j], 8);
    acca[j] += __shfl_xor(acca[j], 16);
    accb[j] += __shfl_xor(accb[j], 16);
    acca[j] += __shfl_xor(acca[j], 32);
    accb[j] += __shfl_xor(accb[j], 32);
  }
  den += __shfl_xor(den, 8);
  den += __shfl_xor(den, 16);
  den += __shfl_xor(den, 32);
  if (s == 0) {
    float inv = 1.0f / (den + 1e-16f);
    f32x4 bva = *(const f32x4*)(bias + 8 * lr);
    f32x4 bvb = *(const f32x4*)(bias + 8 * lr + 4);
    f32x4 oa = acca * inv + bva;
    f32x4 ob = accb * inv + bvb;
    float* op = out + (size_t)w * 64 + 8 * lr;
    *(f32x4*)op = oa;
    *(f32x4*)(op + 4) = ob;
  }
}

extern "C" void kernel_launch(void* const* d_in, const int* in_sizes, int n_in,
                              void* d_out, int out_size, void* d_ws, size_t ws_size,
                              hipStream_t stream) {
  const float* x = (const float*)d_in[0];
  const int* eidx = (const int*)d_in[1];  // int32 per harness conversion
  const float* W = (const float*)d_in[2];
  const float* att = (const float*)d_in[3];
  const float* bias = (const float*)d_in[4];
  float* out = (float*)d_out;

  const int N = in_sizes[0] / 128;
  const int E = in_sizes[1] / 2;
  const int NBKT = (N + 511) >> 9;
  int Cedge = (E + NBKT - 1) / NBKT;
  Cedge = Cedge + Cedge / 8 + 64;  // ~12.5% slack (12+ sigma for random rows)
  Cedge = (Cedge + 15) & ~15;
  if (Cedge > STAGE_CAP) Cedge = STAGE_CAP;
  const int Ctot = Cedge + 512;  // + self-loop slots

  unsigned short* hb = (unsigned short*)d_ws;          // N*64*2 = 12.8 MB
  int* bucket_fill = (int*)(hb + (size_t)N * 64);      // NBKT_MAX ints
  int2* rowinfo = (int2*)(bucket_fill + NBKT_MAX);     // N int2
  unsigned* bucket_arr = (unsigned*)(rowinfo + N);     // NBKT*Ctot u32 (~7.6 MB)

  hipMemsetAsync(bucket_fill, 0, NBKT_MAX * sizeof(int), stream);

  gemm_mfma<<<(N + 255) / 256, 256, 0, stream>>>(x, W, hb, N);
  bucket_pass<<<(E + TILE - 1) / TILE, 256, 0, stream>>>(eidx, eidx + E, bucket_fill,
                                                         bucket_arr, E, Cedge, Ctot, NBKT);
  csr_pass<<<NBKT, 256, 0, stream>>>(bucket_arr, bucket_fill, rowinfo, Cedge, Ctot, N);
  node_pass<<<(N * 64 + 255) / 256, 256, 0, stream>>>(hb, rowinfo, bucket_arr, att, bias,
                                                      out, N);
}

// Round 10
// 114.373 us; speedup vs baseline: 1.0865x; 1.0865x over previous
//
#include <hip/hip_runtime.h>

#define NEG_SLOPE 0.2f

typedef float f32x4 __attribute__((ext_vector_type(4)));
typedef short bf16x8 __attribute__((ext_vector_type(8)));

// ---- bf16 helpers (raw-bit, RNE) ----
__device__ __forceinline__ unsigned short f2bf(float f) {
  union { float f; unsigned u; } v; v.f = f;
  unsigned r = v.u + 0x7fff + ((v.u >> 16) & 1);
  return (unsigned short)(r >> 16);
}
__device__ __forceinline__ float bf2f(unsigned short u) {
  union { unsigned u; float f; } v; v.u = ((unsigned)u) << 16;
  return v.f;
}
__device__ __forceinline__ unsigned pkbf(float a, float b) {
  return (unsigned)f2bf(a) | ((unsigned)f2bf(b) << 16);
}
__device__ __forceinline__ f32x4 upk4(unsigned ux, unsigned uy) {
  union { unsigned u; float f; } a, b, c, d;
  a.u = ux << 16; b.u = ux & 0xffff0000u;
  c.u = uy << 16; d.u = uy & 0xffff0000u;
  f32x4 r; r.x = a.f; r.y = b.f; r.z = c.f; r.w = d.f;
  return r;
}
// fused |s|*coef + d (abs folds as input modifier)
__device__ __forceinline__ f32x4 absfma(f32x4 s, f32x4 coef, f32x4 d) {
  d.x = fmaf(fabsf(s.x), coef.x, d.x);
  d.y = fmaf(fabsf(s.y), coef.y, d.y);
  d.z = fmaf(fabsf(s.z), coef.z, d.z);
  d.w = fmaf(fabsf(s.w), coef.w, d.w);
  return d;
}
// x + (x from lane^1 / lane^2) via DPP quad_perm — pure VALU, no DS pipe
__device__ __forceinline__ float dpp_xor1_add(float x) {
  int y = __builtin_amdgcn_mov_dpp(__builtin_bit_cast(int, x), 0xB1, 0xF, 0xF, true);
  return x + __builtin_bit_cast(float, y);
}
__device__ __forceinline__ float dpp_xor2_add(float x) {
  int y = __builtin_amdgcn_mov_dpp(__builtin_bit_cast(int, x), 0x4E, 0xF, 0xF, true);
  return x + __builtin_bit_cast(float, y);
}

// -------- MFMA GEMM: hb[N,64](bf16) = x[N,128] @ W[128,64] --------
// mfma_f32_16x16x32_bf16. x split hi+lo bf16 (2 MFMAs) so dot error ~ W only.
__global__ __launch_bounds__(256) void gemm_mfma(const float* __restrict__ x,
                                                 const float* __restrict__ W,
                                                 unsigned short* __restrict__ hb, int N) {
  __shared__ uint4 Bl[1024];  // [ct*4+kt][lane] : 16B B-fragments
  const int t = threadIdx.x;
  {
    const int l = t & 63;
    const int kt = (t >> 6) & 3;
    const int kb = kt * 32 + ((l >> 4) * 8);
    const int cb = l & 15;
#pragma unroll
    for (int ct = 0; ct < 4; ct++) {
      const float* wp = W + (size_t)kb * 64 + ct * 16 + cb;
      unsigned p[4];
#pragma unroll
      for (int jj = 0; jj < 4; jj++)
        p[jj] = pkbf(wp[(2 * jj) * 64], wp[(2 * jj + 1) * 64]);
      Bl[(ct * 4 + kt) * 64 + l] = make_uint4(p[0], p[1], p[2], p[3]);
    }
  }
  __syncthreads();
  const int l = t & 63;
  const int wv = t >> 6;
  union BU { bf16x8 v; uint4 q; };
  BU b[4][4];
#pragma unroll
  for (int ct = 0; ct < 4; ct++)
#pragma unroll
    for (int kt = 0; kt < 4; kt++) b[ct][kt].q = Bl[(ct * 4 + kt) * 64 + l];

  const int rowbase0 = blockIdx.x * 256 + wv * 64;
#pragma unroll
  for (int rt = 0; rt < 4; rt++) {
    const int rbase = rowbase0 + rt * 16;
    int rl = rbase + (l & 15);
    if (rl >= N) rl = N - 1;
    const float* xp = x + (size_t)rl * 128 + ((l >> 4) * 8);
    BU ah[4], alo[4];
#pragma unroll
    for (int kt = 0; kt < 4; kt++) {
      float f[8];
      float4 v0 = *(const float4*)(xp + kt * 32);
      float4 v1 = *(const float4*)(xp + kt * 32 + 4);
      f[0] = v0.x; f[1] = v0.y; f[2] = v0.z; f[3] = v0.w;
      f[4] = v1.x; f[5] = v1.y; f[6] = v1.z; f[7] = v1.w;
      unsigned short hs[8], ls[8];
#pragma unroll
      for (int j = 0; j < 8; j++) {
        hs[j] = f2bf(f[j]);
        ls[j] = f2bf(f[j] - bf2f(hs[j]));
      }
      ah[kt].q = make_uint4(hs[0] | (hs[1] << 16), hs[2] | (hs[3] << 16),
                            hs[4] | (hs[5] << 16), hs[6] | (hs[7] << 16));
      alo[kt].q = make_uint4(ls[0] | (ls[1] << 16), ls[2] | (ls[3] << 16),
                             ls[4] | (ls[5] << 16), ls[6] | (ls[7] << 16));
    }
#pragma unroll
    for (int ct = 0; ct < 4; ct++) {
      f32x4 acc = {0.f, 0.f, 0.f, 0.f};
#pragma unroll
      for (int kt = 0; kt < 4; kt++) {
        acc = __builtin_amdgcn_mfma_f32_16x16x32_bf16(ah[kt].v, b[ct][kt].v, acc, 0, 0, 0);
        acc = __builtin_amdgcn_mfma_f32_16x16x32_bf16(alo[kt].v, b[ct][kt].v, acc, 0, 0, 0);
      }
#pragma unroll
      for (int j = 0; j < 4; j++) {
        float v = acc[j];
        float pv = __shfl_xor(v, 1);
        int row = rbase + (l >> 4) * 4 + j;
        if (!(l & 1) && row < N) {
          *(unsigned*)((char*)hb + (size_t)row * 128 + ct * 32 + (l & 15) * 2) =
              pkbf(v, pv);
        }
      }
    }
  }
}

// -------- Pass 1: bucket edges by row>>9, LDS-compacted writes --------
#define TILE 4096
#define EPT 16
#define NBKT_MAX 256

__global__ __launch_bounds__(256) void bucket_pass(const int* __restrict__ rowi,
                                                   const int* __restrict__ coli,
                                                   int* __restrict__ bucket_fill,
                                                   unsigned* __restrict__ bucket_arr,
                                                   int E, int Cedge, int Ctot, int NBKT) {
  __shared__ int cnt[NBKT_MAX];
  __shared__ int excl[NBKT_MAX];
  __shared__ int gadj[NBKT_MAX];
  __shared__ int tmp[NBKT_MAX];
  __shared__ unsigned staged[TILE];
  __shared__ unsigned char bkof[TILE];
  const int t = threadIdx.x;
  const int tile0 = blockIdx.x * TILE;
  const int nt = min(TILE, E - tile0);
  cnt[t] = 0;
  __syncthreads();
  unsigned pk[EPT];
  int bk[EPT];
#pragma unroll
  for (int j = 0; j < EPT; j++) {
    int i = tile0 + j * 256 + t;
    if (i < E) {
      int r = rowi[i];
      int c = coli[i];
      bk[j] = r >> 9;
      pk[j] = ((unsigned)(r & 511) << 17) | (unsigned)c;
      atomicAdd(&cnt[bk[j]], 1);
    } else {
      bk[j] = -1;
    }
  }
  __syncthreads();
  // 256-wide inclusive scan of cnt
  int v = cnt[t];
  tmp[t] = v;
  __syncthreads();
  for (int off = 1; off < 256; off <<= 1) {
    int val = tmp[t] + ((t >= off) ? tmp[t - off] : 0);
    __syncthreads();
    tmp[t] = val;
    __syncthreads();
  }
  int ex = tmp[t] - v;
  excl[t] = ex;
  int ga = 0;
  if (v > 0) ga = atomicAdd(&bucket_fill[t], v);
  gadj[t] = ga - ex;  // global_pos_in_bucket = local_stage_idx + gadj[b]
  cnt[t] = ex;        // cursor
  __syncthreads();
  // scatter into LDS stage (grouped by bucket)
#pragma unroll
  for (int j = 0; j < EPT; j++) {
    if (bk[j] >= 0) {
      int lp = atomicAdd(&cnt[bk[j]], 1);
      staged[lp] = pk[j];
      bkof[lp] = (unsigned char)bk[j];
    }
  }
  __syncthreads();
  // monotonic copy-out
  for (int i = t; i < nt; i += 256) {
    int b = bkof[i];
    int pb = i + gadj[b];
    if (pb < Cedge) bucket_arr[b * Ctot + pb] = staged[i];
  }
}

// -------- Pass 2: per-bucket counting sort -> CSR (in-place), 1024 thr -----
// hist init = 1 per valid row (self-loop slot); self entry appended after
// the edge scatter. rowinfo[r] = {offs, end} packed int2.
#define STAGE_CAP 10240

__global__ __launch_bounds__(1024) void csr_pass(unsigned* __restrict__ bucket_arr,
                                                 const int* __restrict__ bucket_fill,
                                                 int2* __restrict__ rowinfo,
                                                 int Cedge, int Ctot, int N) {
  __shared__ unsigned stage[STAGE_CAP];
  __shared__ int hist[512], excl[512], pairs[256];
  const int t = threadIdx.x;
  const int b = blockIdx.x;
  const int bb = b * Ctot;
  const int r0 = b << 9;
  const int nb = min(bucket_fill[b], Cedge);
  for (int i = t; i < 512; i += 1024) hist[i] = ((r0 + i) < N) ? 1 : 0;  // self slot
  for (int i = t; i < nb; i += 1024) stage[i] = bucket_arr[bb + i];
  __syncthreads();
  for (int i = t; i < nb; i += 1024) atomicAdd(&hist[stage[i] >> 17], 1);
  __syncthreads();
  int h0 = 0, h1 = 0, ps = 0;
  if (t < 256) {
    h0 = hist[2 * t];
    h1 = hist[2 * t + 1];
    ps = h0 + h1;
    pairs[t] = ps;
  }
  __syncthreads();
  for (int off = 1; off < 256; off <<= 1) {
    int val = 0;
    if (t < 256) val = pairs[t] + ((t >= off) ? pairs[t - off] : 0);
    __syncthreads();
    if (t < 256) pairs[t] = val;
    __syncthreads();
  }
  if (t < 256) {
    int pexcl = pairs[t] - ps;
    excl[2 * t] = pexcl;
    excl[2 * t + 1] = pexcl + h0;
  }
  __syncthreads();
  for (int r = t; r < 512; r += 1024) {
    int gr = r0 + r;
    if (gr < N) {
      int o = bb + excl[r];
      rowinfo[gr] = make_int2(o, o + hist[r]);
    }
  }
  __syncthreads();
  for (int i = t; i < nb; i += 1024) {
    unsigned pk = stage[i];
    int r = pk >> 17;
    int lp = atomicAdd(&excl[r], 1);
    bucket_arr[bb + lp] = (pk & 0x1FFFFu) << 7;  // pre-scaled byte offset
  }
  __syncthreads();
  // append self entries (cursor now = offs + nedges = last slot)
  for (int r = t; r < 512; r += 1024) {
    int gr = r0 + r;
    if (gr < N) bucket_arr[bb + excl[r]] = (unsigned)gr << 7;
  }
}

// -------- Node pass: one wave/node, 4 ch/lane, 4 edge streams --------
// lane = q*16+lr: lr owns channels 4lr..4lr+3 (head = lr>>2), quarter q owns
// edge stream q. Head reduce = 2 DPP quad-perm adds (no DS pipe). leaky*att
// folded: attA*s + attB*|s| (attA=0.6att, attB=0.4att). srcs stream software-
// pipelined: next chunk's indices load while current chunk gathers.
#define ESTEP(u)                                        \
  {                                                     \
    f32x4 jv = upk4((u).x, (u).y);                      \
    f32x4 s = hiv + jv;                                 \
    f32x4 d = s * attA;                                 \
    d = absfma(s, attB, d);                             \
    float al = (d.x + d.y) + (d.z + d.w);               \
    al = dpp_xor1_add(al);                              \
    al = dpp_xor2_add(al);                              \
    float p = __expf(al);                               \
    acc += jv * p;                                      \
    den += p;                                           \
  }

__global__ __launch_bounds__(256) void node_pass(const unsigned short* __restrict__ hb,
                                                 const int2* __restrict__ rowinfo,
                                                 const unsigned* __restrict__ srcs,
                                                 const float* __restrict__ att,
                                                 const float* __restrict__ bias,
                                                 float* __restrict__ out, int N) {
  int w = (blockIdx.x * blockDim.x + threadIdx.x) >> 6;
  if (w >= N) return;
  const int lane = threadIdx.x & 63;
  const int lr = lane & 15;
  const int q = lane >> 4;
  const char* hbc = (const char*)hb;
  const unsigned loff = (unsigned)(lr << 3);
  const f32x4 attv = *(const f32x4*)(att + 4 * lr);
  const f32x4 attA = attv * 0.6f;
  const f32x4 attB = attv * 0.4f;
  const int2 oi = rowinfo[w];
  int k = oi.x;
  const int k1 = oi.y;
  uint2 hu = *(const uint2*)(hbc + (((unsigned)w << 7) | loff));
  const f32x4 hiv = upk4(hu.x, hu.y);
  f32x4 acc = {0.f, 0.f, 0.f, 0.f};
  float den = 0.f;
  // software-pipelined 16-edge chunks
  unsigned s0, s1, s2, s3;
  if (k + 16 <= k1) {
    s0 = srcs[k + q];
    s1 = srcs[k + 4 + q];
    s2 = srcs[k + 8 + q];
    s3 = srcs[k + 12 + q];
  }
  for (; k + 32 <= k1; k += 16) {
    unsigned n0 = srcs[k + 16 + q];
    unsigned n1 = srcs[k + 20 + q];
    unsigned n2 = srcs[k + 24 + q];
    unsigned n3 = srcs[k + 28 + q];
    uint2 u0 = *(const uint2*)(hbc + (s0 | loff));
    uint2 u1 = *(const uint2*)(hbc + (s1 | loff));
    uint2 u2 = *(const uint2*)(hbc + (s2 | loff));
    uint2 u3 = *(const uint2*)(hbc + (s3 | loff));
    ESTEP(u0);
    ESTEP(u1);
    ESTEP(u2);
    ESTEP(u3);
    s0 = n0; s1 = n1; s2 = n2; s3 = n3;
  }
  if (k + 16 <= k1) {
    uint2 u0 = *(const uint2*)(hbc + (s0 | loff));
    uint2 u1 = *(const uint2*)(hbc + (s1 | loff));
    uint2 u2 = *(const uint2*)(hbc + (s2 | loff));
    uint2 u3 = *(const uint2*)(hbc + (s3 | loff));
    ESTEP(u0);
    ESTEP(u1);
    ESTEP(u2);
    ESTEP(u3);
    k += 16;
  }
  for (; k + 4 <= k1; k += 4) {
    unsigned o = srcs[k + q] | loff;
    uint2 u = *(const uint2*)(hbc + o);
    ESTEP(u);
  }
  if (k < k1) {
    int kk = k + q;
    bool act = kk < k1;
    unsigned o = (act ? srcs[kk] : srcs[k]) | loff;
    uint2 u = *(const uint2*)(hbc + o);
    f32x4 jv = upk4(u.x, u.y);
    f32x4 s = hiv + jv;
    f32x4 d = s * attA;
    d = absfma(s, attB, d);
    float al = (d.x + d.y) + (d.z + d.w);
    al = dpp_xor1_add(al);
    al = dpp_xor2_add(al);
    float p = act ? __expf(al) : 0.f;
    acc += jv * p;
    den += p;
  }
  // combine 4 streams
  acc.x += __shfl_xor(acc.x, 16); acc.y += __shfl_xor(acc.y, 16);
  acc.z += __shfl_xor(acc.z, 16); acc.w += __shfl_xor(acc.w, 16);
  den += __shfl_xor(den, 16);
  acc.x += __shfl_xor(acc.x, 32); acc.y += __shfl_xor(acc.y, 32);
  acc.z += __shfl_xor(acc.z, 32); acc.w += __shfl_xor(acc.w, 32);
  den += __shfl_xor(den, 32);
  if (q == 0) {
    float inv = 1.0f / (den + 1e-16f);
    f32x4 bv = *(const f32x4*)(bias + 4 * lr);
    f32x4 o = acc * inv + bv;
    *(f32x4*)(out + (size_t)w * 64 + 4 * lr) = o;
  }
}

extern "C" void kernel_launch(void* const* d_in, const int* in_sizes, int n_in,
                              void* d_out, int out_size, void* d_ws, size_t ws_size,
                              hipStream_t stream) {
  const float* x = (const float*)d_in[0];
  const int* eidx = (const int*)d_in[1];  // int32 per harness conversion
  const float* W = (const float*)d_in[2];
  const float* att = (const float*)d_in[3];
  const float* bias = (const float*)d_in[4];
  float* out = (float*)d_out;

  const int N = in_sizes[0] / 128;
  const int E = in_sizes[1] / 2;
  const int NBKT = (N + 511) >> 9;
  int Cedge = (E + NBKT - 1) / NBKT;
  Cedge = Cedge + Cedge / 8 + 64;  // ~12.5% slack (12+ sigma for random rows)
  Cedge = (Cedge + 15) & ~15;
  if (Cedge > STAGE_CAP) Cedge = STAGE_CAP;
  const int Ctot = Cedge + 512;  // + self-loop slots

  unsigned short* hb = (unsigned short*)d_ws;          // N*64*2 = 12.8 MB
  int* bucket_fill = (int*)(hb + (size_t)N * 64);      // NBKT_MAX ints
  int2* rowinfo = (int2*)(bucket_fill + NBKT_MAX);     // N int2
  unsigned* bucket_arr = (unsigned*)(rowinfo + N);     // NBKT*Ctot u32 (~7.6 MB)

  hipMemsetAsync(bucket_fill, 0, NBKT_MAX * sizeof(int), stream);

  gemm_mfma<<<(N + 255) / 256, 256, 0, stream>>>(x, W, hb, N);
  bucket_pass<<<(E + TILE - 1) / TILE, 256, 0, stream>>>(eidx, eidx + E, bucket_fill,
                                                         bucket_arr, E, Cedge, Ctot, NBKT);
  csr_pass<<<NBKT, 1024, 0, stream>>>(bucket_arr, bucket_fill, rowinfo, Cedge, Ctot, N);
  node_pass<<<(N * 64 + 255) / 256, 256, 0, stream>>>(hb, rowinfo, bucket_arr, att, bias,
                                                      out, N);
}

// Round 11
// 101.047 us; speedup vs baseline: 1.2298x; 1.1319x over previous
//
#include <hip/hip_runtime.h>

#define NEG_SLOPE 0.2f

typedef float f32x4 __attribute__((ext_vector_type(4)));
typedef short bf16x8 __attribute__((ext_vector_type(8)));

// ---- bf16 helpers (raw-bit, RNE) ----
__device__ __forceinline__ unsigned short f2bf(float f) {
  union { float f; unsigned u; } v; v.f = f;
  unsigned r = v.u + 0x7fff + ((v.u >> 16) & 1);
  return (unsigned short)(r >> 16);
}
__device__ __forceinline__ float bf2f(unsigned short u) {
  union { unsigned u; float f; } v; v.u = ((unsigned)u) << 16;
  return v.f;
}
__device__ __forceinline__ unsigned pkbf(float a, float b) {
  return (unsigned)f2bf(a) | ((unsigned)f2bf(b) << 16);
}
__device__ __forceinline__ f32x4 upk4(unsigned ux, unsigned uy) {
  union { unsigned u; float f; } a, b, c, d;
  a.u = ux << 16; b.u = ux & 0xffff0000u;
  c.u = uy << 16; d.u = uy & 0xffff0000u;
  f32x4 r; r.x = a.f; r.y = b.f; r.z = c.f; r.w = d.f;
  return r;
}
__device__ __forceinline__ f32x4 absfma(f32x4 s, f32x4 coef, f32x4 d) {
  d.x = fmaf(fabsf(s.x), coef.x, d.x);
  d.y = fmaf(fabsf(s.y), coef.y, d.y);
  d.z = fmaf(fabsf(s.z), coef.z, d.z);
  d.w = fmaf(fabsf(s.w), coef.w, d.w);
  return d;
}
// x + (x from lane^1 / lane^2) via DPP quad_perm — pure VALU, no DS pipe
__device__ __forceinline__ float dpp_xor1_add(float x) {
  int y = __builtin_amdgcn_mov_dpp(__builtin_bit_cast(int, x), 0xB1, 0xF, 0xF, true);
  return x + __builtin_bit_cast(float, y);
}
__device__ __forceinline__ float dpp_xor2_add(float x) {
  int y = __builtin_amdgcn_mov_dpp(__builtin_bit_cast(int, x), 0x4E, 0xF, 0xF, true);
  return x + __builtin_bit_cast(float, y);
}

// ================= Fused K1: gemm blocks [0,G1) || bucket blocks [G1,G1+G2) =
#define TILE 4096
#define EPT 16
#define NBKT_MAX 256
#define SMEM_BYTES 24576

// -------- gemm role: hb[N,64](bf16) = x[N,128] @ W[128,64] (MFMA) --------
__device__ __forceinline__ void gemm_role(const float* __restrict__ x,
                                          const float* __restrict__ W,
                                          unsigned short* __restrict__ hb, int N,
                                          char* smem, int bid) {
  uint4* Bl = (uint4*)smem;  // 1024 uint4 = 16 KB
  const int t = threadIdx.x;
  {
    const int l = t & 63;
    const int kt = (t >> 6) & 3;
    const int kb = kt * 32 + ((l >> 4) * 8);
    const int cb = l & 15;
#pragma unroll
    for (int ct = 0; ct < 4; ct++) {
      const float* wp = W + (size_t)kb * 64 + ct * 16 + cb;
      unsigned p[4];
#pragma unroll
      for (int jj = 0; jj < 4; jj++)
        p[jj] = pkbf(wp[(2 * jj) * 64], wp[(2 * jj + 1) * 64]);
      Bl[(ct * 4 + kt) * 64 + l] = make_uint4(p[0], p[1], p[2], p[3]);
    }
  }
  __syncthreads();
  const int l = t & 63;
  const int wv = t >> 6;
  union BU { bf16x8 v; uint4 q; };
  BU b[4][4];
#pragma unroll
  for (int ct = 0; ct < 4; ct++)
#pragma unroll
    for (int kt = 0; kt < 4; kt++) b[ct][kt].q = Bl[(ct * 4 + kt) * 64 + l];

  const int rowbase0 = bid * 256 + wv * 64;
#pragma unroll
  for (int rt = 0; rt < 4; rt++) {
    const int rbase = rowbase0 + rt * 16;
    int rl = rbase + (l & 15);
    if (rl >= N) rl = N - 1;
    const float* xp = x + (size_t)rl * 128 + ((l >> 4) * 8);
    BU ah[4], alo[4];
#pragma unroll
    for (int kt = 0; kt < 4; kt++) {
      float f[8];
      float4 v0 = *(const float4*)(xp + kt * 32);
      float4 v1 = *(const float4*)(xp + kt * 32 + 4);
      f[0] = v0.x; f[1] = v0.y; f[2] = v0.z; f[3] = v0.w;
      f[4] = v1.x; f[5] = v1.y; f[6] = v1.z; f[7] = v1.w;
      unsigned short hs[8], ls[8];
#pragma unroll
      for (int j = 0; j < 8; j++) {
        hs[j] = f2bf(f[j]);
        ls[j] = f2bf(f[j] - bf2f(hs[j]));
      }
      ah[kt].q = make_uint4(hs[0] | (hs[1] << 16), hs[2] | (hs[3] << 16),
                            hs[4] | (hs[5] << 16), hs[6] | (hs[7] << 16));
      alo[kt].q = make_uint4(ls[0] | (ls[1] << 16), ls[2] | (ls[3] << 16),
                             ls[4] | (ls[5] << 16), ls[6] | (ls[7] << 16));
    }
#pragma unroll
    for (int ct = 0; ct < 4; ct++) {
      f32x4 acc = {0.f, 0.f, 0.f, 0.f};
#pragma unroll
      for (int kt = 0; kt < 4; kt++) {
        acc = __builtin_amdgcn_mfma_f32_16x16x32_bf16(ah[kt].v, b[ct][kt].v, acc, 0, 0, 0);
        acc = __builtin_amdgcn_mfma_f32_16x16x32_bf16(alo[kt].v, b[ct][kt].v, acc, 0, 0, 0);
      }
#pragma unroll
      for (int j = 0; j < 4; j++) {
        float v = acc[j];
        float pv = __shfl_xor(v, 1);
        int row = rbase + (l >> 4) * 4 + j;
        if (!(l & 1) && row < N) {
          *(unsigned*)((char*)hb + (size_t)row * 128 + ct * 32 + (l & 15) * 2) =
              pkbf(v, pv);
        }
      }
    }
  }
}

// -------- bucket role: bucket edges by row>>9, LDS-compacted writes --------
__device__ __forceinline__ void bucket_role(const int* __restrict__ rowi,
                                            const int* __restrict__ coli,
                                            int* __restrict__ bucket_fill,
                                            unsigned* __restrict__ bucket_arr, int E,
                                            int Cedge, int Ctot, int NBKT, char* smem,
                                            int bid) {
  int* cnt = (int*)smem;                       // 256
  int* gadj = cnt + 256;                       // 256
  int* tmp = gadj + 256;                       // 256
  unsigned* staged = (unsigned*)(tmp + 256);   // 4096
  unsigned char* bkof = (unsigned char*)(staged + TILE);  // 4096
  const int t = threadIdx.x;
  const int tile0 = bid * TILE;
  const int nt = min(TILE, E - tile0);
  cnt[t] = 0;
  __syncthreads();
  unsigned pk[EPT];
  int bk[EPT];
#pragma unroll
  for (int j = 0; j < EPT; j++) {
    int i = tile0 + j * 256 + t;
    if (i < E) {
      int r = rowi[i];
      int c = coli[i];
      bk[j] = r >> 9;
      pk[j] = ((unsigned)(r & 511) << 17) | (unsigned)c;
      atomicAdd(&cnt[bk[j]], 1);
    } else {
      bk[j] = -1;
    }
  }
  __syncthreads();
  int v = cnt[t];
  tmp[t] = v;
  __syncthreads();
  for (int off = 1; off < 256; off <<= 1) {
    int val = tmp[t] + ((t >= off) ? tmp[t - off] : 0);
    __syncthreads();
    tmp[t] = val;
    __syncthreads();
  }
  int ex = tmp[t] - v;
  int ga = 0;
  if (v > 0) ga = atomicAdd(&bucket_fill[t], v);
  gadj[t] = ga - ex;
  cnt[t] = ex;  // cursor
  __syncthreads();
#pragma unroll
  for (int j = 0; j < EPT; j++) {
    if (bk[j] >= 0) {
      int lp = atomicAdd(&cnt[bk[j]], 1);
      staged[lp] = pk[j];
      bkof[lp] = (unsigned char)bk[j];
    }
  }
  __syncthreads();
  for (int i = t; i < nt; i += 256) {
    int b = bkof[i];
    int pb = i + gadj[b];
    if (pb < Cedge) bucket_arr[b * Ctot + pb] = staged[i];
  }
}

__global__ __launch_bounds__(256) void gemm_bucket(const float* __restrict__ x,
                                                   const float* __restrict__ W,
                                                   unsigned short* __restrict__ hb, int N,
                                                   const int* __restrict__ rowi,
                                                   const int* __restrict__ coli,
                                                   int* __restrict__ bucket_fill,
                                                   unsigned* __restrict__ bucket_arr,
                                                   int E, int Cedge, int Ctot, int NBKT,
                                                   int G1) {
  __shared__ __align__(16) char smem[SMEM_BYTES];
  if ((int)blockIdx.x < G1)
    gemm_role(x, W, hb, N, smem, blockIdx.x);
  else
    bucket_role(rowi, coli, bucket_fill, bucket_arr, E, Cedge, Ctot, NBKT, smem,
                blockIdx.x - G1);
}

// -------- Pass 2: per-bucket counting sort -> CSR (in-place), 1024 thr -----
#define STAGE_CAP 10240

__global__ __launch_bounds__(1024) void csr_pass(unsigned* __restrict__ bucket_arr,
                                                 const int* __restrict__ bucket_fill,
                                                 int2* __restrict__ rowinfo,
                                                 int Cedge, int Ctot, int N) {
  __shared__ unsigned stage[STAGE_CAP];
  __shared__ int hist[512], excl[512], pairs[256];
  const int t = threadIdx.x;
  const int b = blockIdx.x;
  const int bb = b * Ctot;
  const int r0 = b << 9;
  const int nb = min(bucket_fill[b], Cedge);
  for (int i = t; i < 512; i += 1024) hist[i] = ((r0 + i) < N) ? 1 : 0;  // self slot
  for (int i = t; i < nb; i += 1024) stage[i] = bucket_arr[bb + i];
  __syncthreads();
  for (int i = t; i < nb; i += 1024) atomicAdd(&hist[stage[i] >> 17], 1);
  __syncthreads();
  int h0 = 0, h1 = 0, ps = 0;
  if (t < 256) {
    h0 = hist[2 * t];
    h1 = hist[2 * t + 1];
    ps = h0 + h1;
    pairs[t] = ps;
  }
  __syncthreads();
  for (int off = 1; off < 256; off <<= 1) {
    int val = 0;
    if (t < 256) val = pairs[t] + ((t >= off) ? pairs[t - off] : 0);
    __syncthreads();
    if (t < 256) pairs[t] = val;
    __syncthreads();
  }
  if (t < 256) {
    int pexcl = pairs[t] - ps;
    excl[2 * t] = pexcl;
    excl[2 * t + 1] = pexcl + h0;
  }
  __syncthreads();
  for (int r = t; r < 512; r += 1024) {
    int gr = r0 + r;
    if (gr < N) {
      int o = bb + excl[r];
      rowinfo[gr] = make_int2(o, o + hist[r]);
    }
  }
  __syncthreads();
  for (int i = t; i < nb; i += 1024) {
    unsigned pk = stage[i];
    int r = pk >> 17;
    int lp = atomicAdd(&excl[r], 1);
    bucket_arr[bb + lp] = (pk & 0x1FFFFu) << 7;  // pre-scaled byte offset
  }
  __syncthreads();
  for (int r = t; r < 512; r += 1024) {
    int gr = r0 + r;
    if (gr < N) bucket_arr[bb + excl[r]] = (unsigned)gr << 7;
  }
}

// -------- Node pass: one wave per TWO nodes, 4 ch/lane, 4 edge streams -----
// Dual-node ILP: prologue loads for both nodes issue together; main loop
// keeps 4 gathers (2 per node) in flight. DPP quad-perm head reduce.
#define ESTEPN(hivX, accX, denX, u)                     \
  {                                                     \
    f32x4 jv = upk4((u).x, (u).y);                      \
    f32x4 s = hivX + jv;                                \
    f32x4 d = s * attA;                                 \
    d = absfma(s, attB, d);                             \
    float al = (d.x + d.y) + (d.z + d.w);               \
    al = dpp_xor1_add(al);                              \
    al = dpp_xor2_add(al);                              \
    float p = __expf(al);                               \
    accX += jv * p;                                     \
    denX += p;                                          \
  }

__global__ __launch_bounds__(256) void node_pass(const unsigned short* __restrict__ hb,
                                                 const int2* __restrict__ rowinfo,
                                                 const unsigned* __restrict__ srcs,
                                                 const float* __restrict__ att,
                                                 const float* __restrict__ bias,
                                                 float* __restrict__ out, int N) {
  const int wp = (blockIdx.x * blockDim.x + threadIdx.x) >> 6;  // wave pair id
  const int a = wp * 2;
  if (a >= N) return;
  const int bn = a + 1;
  const bool bvalid = bn < N;
  const int bc = bvalid ? bn : a;
  const int lane = threadIdx.x & 63;
  const int lr = lane & 15;
  const int q = lane >> 4;
  const char* hbc = (const char*)hb;
  const unsigned loff = (unsigned)(lr << 3);
  const f32x4 attv = *(const f32x4*)(att + 4 * lr);
  const f32x4 attA = attv * 0.6f;
  const f32x4 attB = attv * 0.4f;
  const int2 ria = rowinfo[a];
  const int2 rib = rowinfo[bc];
  uint2 hua = *(const uint2*)(hbc + (((unsigned)a << 7) | loff));
  uint2 hub = *(const uint2*)(hbc + (((unsigned)bc << 7) | loff));
  const f32x4 hivA = upk4(hua.x, hua.y);
  const f32x4 hivB = upk4(hub.x, hub.y);
  int ka = ria.x, kb = rib.x;
  const int ka1 = ria.y;
  const int kb1 = bvalid ? rib.y : rib.x;  // b empty if invalid
  f32x4 accA = {0.f, 0.f, 0.f, 0.f};
  f32x4 accB = {0.f, 0.f, 0.f, 0.f};
  float denA = 0.f, denB = 0.f;
  // paired main loop: 8 edges per node per iter, 4 gathers in flight
  while (ka + 8 <= ka1 && kb + 8 <= kb1) {
    unsigned oa0 = srcs[ka + q] | loff;
    unsigned oa1 = srcs[ka + 4 + q] | loff;
    unsigned ob0 = srcs[kb + q] | loff;
    unsigned ob1 = srcs[kb + 4 + q] | loff;
    uint2 ua0 = *(const uint2*)(hbc + oa0);
    uint2 ua1 = *(const uint2*)(hbc + oa1);
    uint2 ub0 = *(const uint2*)(hbc + ob0);
    uint2 ub1 = *(const uint2*)(hbc + ob1);
    ESTEPN(hivA, accA, denA, ua0);
    ESTEPN(hivA, accA, denA, ua1);
    ESTEPN(hivB, accB, denB, ub0);
    ESTEPN(hivB, accB, denB, ub1);
    ka += 8;
    kb += 8;
  }
  // drain A
  for (; ka + 8 <= ka1; ka += 8) {
    unsigned o0 = srcs[ka + q] | loff;
    unsigned o1 = srcs[ka + 4 + q] | loff;
    uint2 u0 = *(const uint2*)(hbc + o0);
    uint2 u1 = *(const uint2*)(hbc + o1);
    ESTEPN(hivA, accA, denA, u0);
    ESTEPN(hivA, accA, denA, u1);
  }
  // drain B
  for (; kb + 8 <= kb1; kb += 8) {
    unsigned o0 = srcs[kb + q] | loff;
    unsigned o1 = srcs[kb + 4 + q] | loff;
    uint2 u0 = *(const uint2*)(hbc + o0);
    uint2 u1 = *(const uint2*)(hbc + o1);
    ESTEPN(hivB, accB, denB, u0);
    ESTEPN(hivB, accB, denB, u1);
  }
  // tails (0-7 edges each)
  for (; ka + 4 <= ka1; ka += 4) {
    unsigned o = srcs[ka + q] | loff;
    uint2 u = *(const uint2*)(hbc + o);
    ESTEPN(hivA, accA, denA, u);
  }
  for (; kb + 4 <= kb1; kb += 4) {
    unsigned o = srcs[kb + q] | loff;
    uint2 u = *(const uint2*)(hbc + o);
    ESTEPN(hivB, accB, denB, u);
  }
  if (ka < ka1) {
    bool act = (ka + q) < ka1;
    unsigned o = (act ? srcs[ka + q] : srcs[ka]) | loff;
    uint2 u = *(const uint2*)(hbc + o);
    f32x4 jv = upk4(u.x, u.y);
    f32x4 s = hivA + jv;
    f32x4 d = s * attA;
    d = absfma(s, attB, d);
    float al = (d.x + d.y) + (d.z + d.w);
    al = dpp_xor1_add(al);
    al = dpp_xor2_add(al);
    float p = act ? __expf(al) : 0.f;
    accA += jv * p;
    denA += p;
  }
  if (kb < kb1) {
    bool act = (kb + q) < kb1;
    unsigned o = (act ? srcs[kb + q] : srcs[kb]) | loff;
    uint2 u = *(const uint2*)(hbc + o);
    f32x4 jv = upk4(u.x, u.y);
    f32x4 s = hivB + jv;
    f32x4 d = s * attA;
    d = absfma(s, attB, d);
    float al = (d.x + d.y) + (d.z + d.w);
    al = dpp_xor1_add(al);
    al = dpp_xor2_add(al);
    float p = act ? __expf(al) : 0.f;
    accB += jv * p;
    denB += p;
  }
  // combine 4 streams (both nodes)
#pragma unroll
  for (int j = 0; j < 4; j++) {
    accA[j] += __shfl_xor(accA[j], 16);
    accB[j] += __shfl_xor(accB[j], 16);
    accA[j] += __shfl_xor(accA[j], 32);
    accB[j] += __shfl_xor(accB[j], 32);
  }
  denA += __shfl_xor(denA, 16);
  denB += __shfl_xor(denB, 16);
  denA += __shfl_xor(denA, 32);
  denB += __shfl_xor(denB, 32);
  if (q == 0) {
    const f32x4 bv = *(const f32x4*)(bias + 4 * lr);
    float invA = 1.0f / (denA + 1e-16f);
    f32x4 oa = accA * invA + bv;
    *(f32x4*)(out + (size_t)a * 64 + 4 * lr) = oa;
    if (bvalid) {
      float invB = 1.0f / (denB + 1e-16f);
      f32x4 ob = accB * invB + bv;
      *(f32x4*)(out + (size_t)bn * 64 + 4 * lr) = ob;
    }
  }
}

extern "C" void kernel_launch(void* const* d_in, const int* in_sizes, int n_in,
                              void* d_out, int out_size, void* d_ws, size_t ws_size,
                              hipStream_t stream) {
  const float* x = (const float*)d_in[0];
  const int* eidx = (const int*)d_in[1];  // int32 per harness conversion
  const float* W = (const float*)d_in[2];
  const float* att = (const float*)d_in[3];
  const float* bias = (const float*)d_in[4];
  float* out = (float*)d_out;

  const int N = in_sizes[0] / 128;
  const int E = in_sizes[1] / 2;
  const int NBKT = (N + 511) >> 9;
  int Cedge = (E + NBKT - 1) / NBKT;
  Cedge = Cedge + Cedge / 8 + 64;  // ~12.5% slack (12+ sigma for random rows)
  Cedge = (Cedge + 15) & ~15;
  if (Cedge > STAGE_CAP) Cedge = STAGE_CAP;
  const int Ctot = Cedge + 512;  // + self-loop slots

  unsigned short* hb = (unsigned short*)d_ws;          // N*64*2 = 12.8 MB
  int* bucket_fill = (int*)(hb + (size_t)N * 64);      // NBKT_MAX ints
  int2* rowinfo = (int2*)(bucket_fill + NBKT_MAX);     // N int2
  unsigned* bucket_arr = (unsigned*)(rowinfo + N);     // NBKT*Ctot u32 (~7.6 MB)

  hipMemsetAsync(bucket_fill, 0, NBKT_MAX * sizeof(int), stream);

  const int G1 = (N + 255) / 256;
  const int G2 = (E + TILE - 1) / TILE;
  gemm_bucket<<<G1 + G2, 256, 0, stream>>>(x, W, hb, N, eidx, eidx + E, bucket_fill,
                                           bucket_arr, E, Cedge, Ctot, NBKT, G1);
  csr_pass<<<NBKT, 1024, 0, stream>>>(bucket_arr, bucket_fill, rowinfo, Cedge, Ctot, N);
  const int npairs = (N + 1) / 2;
  node_pass<<<(npairs * 64 + 255) / 256, 256, 0, stream>>>(hb, rowinfo, bucket_arr, att,
                                                           bias, out, N);
}